// Round 2
// baseline (233.184 us; speedup 1.0000x reference)
//
#include <hip/hip_runtime.h>
#include <stdint.h>

typedef __bf16 bf16x8 __attribute__((ext_vector_type(8)));
typedef float  f32x4  __attribute__((ext_vector_type(4)));

static constexpr int Bn = 32, Cn = 128, Hn = 64, Wn = 64, HWn = 4096;
static constexpr size_t OFF_WF    = 0;                        // 221,184 B (B-fragment-ordered weights)
static constexpr size_t OFF_IDX   = 221184;                   // 1,536 B
static constexpr size_t OFF_M     = 229376;                   // 33,554,432 B (median result, bf16, NCHW)
static constexpr size_t OFF_STATS = 33783808;                 // 1,024 B
static constexpr size_t OFF_BN    = 33784832;                 // 1,024 B

__device__ __forceinline__ unsigned short f32_to_bf16(float f) {
    union { float f; unsigned u; } v; v.f = f;
    unsigned u = v.u;
    return (unsigned short)((u + 0x7FFFu + ((u >> 16) & 1u)) >> 16);
}
__device__ __forceinline__ float bf16_to_f32(unsigned short h) {
    union { unsigned u; float f; } v; v.u = ((unsigned)h) << 16;
    return v.f;
}

// ---- K1a: recover idx[j][c] from one-hot hs (3,32,128) ----
__global__ void k_idx(const float* __restrict__ hs, int* __restrict__ idx) {
    int t = blockIdx.x * 256 + threadIdx.x;
    if (t >= 384) return;
    int j = t >> 7, c = t & 127;
    int found = 0;
    for (int d = 0; d < 32; ++d)
        if (hs[(j * 32 + d) * 128 + c] > 0.5f) found = d;
    idx[t] = found;
}

// ---- K1b: sketched weights in MFMA B-fragment order ----
// layout: f = ((q*9+t)*6+nt)*512 + lane*8 + jj holds B[k=(lane>>4)*8+jj][n=nt*16+(lane&15)]
// where k = ci within chunk q, n = j*32+d output channel, t = kh*3+kw
__global__ __launch_bounds__(256) void k_wsk(const float* __restrict__ w2,
                                             const float* __restrict__ hs,
                                             const float* __restrict__ ss,
                                             unsigned short* __restrict__ wf) {
    int f = blockIdx.x * 256 + threadIdx.x;   // 110592 total
    int jj   = f & 7;
    int lane = (f >> 3) & 63;
    int nt   = (f >> 9) % 6;
    int qt   = f / (512 * 6);
    int t    = qt % 9;
    int q    = qt / 9;
    int k  = ((lane >> 4) << 3) + jj;
    int ci = q * 32 + k;
    int n  = nt * 16 + (lane & 15);
    int j = n >> 5, d = n & 31;
    float sum = 0.f;
    for (int c = 0; c < 128; ++c) {
        float g = hs[(j * 32 + d) * 128 + c];
        if (g != 0.f) sum += g * ss[j * 128 + c] * w2[(c * 128 + ci) * 9 + t];
    }
    wf[f] = f32_to_bf16(sum);
}

// ---- K2: conv(96ch) + unsketch + median3 -> m (bf16, NCHW) ----
// grid 512 = b*16 + tile; tile = 4 rows x 64 cols; 512 threads = 8 waves.
// Wave wv owns row (wv>>1), col-half (wv&1)*32 : 2 M-tiles x 6 N-tiles.
// K-chunks q=0..3 (32 ci each) double-buffered in LDS; staging reads x fp32
// (NCHW) directly and converts to bf16 (no separate transpose pass).
__global__ __launch_bounds__(512, 4) void k_conv(const float* __restrict__ x,
                                                 const unsigned short* __restrict__ wf,
                                                 const int* __restrict__ idx,
                                                 unsigned short* __restrict__ m_out) {
    __shared__ __align__(16) unsigned short sm[31680];  // 2 x 15840-elem staging bufs; y-tile (25088) aliases
    __shared__ int   idx_sh[384];
    __shared__ float ss_sh[384];
    int tid  = threadIdx.x;
    int blk  = blockIdx.x;
    int tile = blk & 15, b = blk >> 4;
    int ty0  = tile * 4;
    int wv   = tid >> 6, lane = tid & 63;
    int quad = lane >> 4, l15 = lane & 15;
    int py   = wv >> 1, xh = (wv & 1) * 32;

    for (int i = tid; i < 384; i += 512) {
        idx_sh[i] = idx[i];
        // reuse: ss values are only needed in epilogue; load via idx kernel's ss input
    }

    f32x4 acc[2][6];
#pragma unroll
    for (int a = 0; a < 2; ++a)
#pragma unroll
        for (int nb = 0; nb < 6; ++nb) acc[a][nb] = (f32x4){0.f, 0.f, 0.f, 0.f};

    // ---- staging helper (inlined twice): stage chunk q into buf ----
    // 396 records (6 rows x 66 cols) x 4 octets of 8 ci
#define STAGE(Q, BUF)                                                                   \
    {                                                                                   \
        unsigned short* sb_ = (BUF);                                                    \
        _Pragma("unroll")                                                               \
        for (int t0 = 0; t0 < 1584; t0 += 512) {                                        \
            int t = t0 + tid;                                                           \
            if (t < 1584) {                                                             \
                int r = t >> 2, oct = t & 3;                                            \
                int hy = r / 66, hx = r - hy * 66;                                      \
                int gy = ty0 + hy - 1, gx = hx - 1;                                     \
                unsigned short tmp[8];                                                  \
                if ((unsigned)gy < 64u && (unsigned)gx < 64u) {                         \
                    const float* xp = x + ((size_t)((b * 4 + (Q)) * 32 + oct * 8) << 12) \
                                        + gy * 64 + gx;                                 \
                    _Pragma("unroll")                                                   \
                    for (int i = 0; i < 8; ++i) tmp[i] = f32_to_bf16(xp[(size_t)i << 12]); \
                } else {                                                                \
                    _Pragma("unroll")                                                   \
                    for (int i = 0; i < 8; ++i) tmp[i] = 0;                             \
                }                                                                       \
                *(uint4*)(&sb_[r * 40 + oct * 8]) = *(const uint4*)tmp;                 \
            }                                                                           \
        }                                                                               \
    }

    STAGE(0, sm);
#pragma unroll
    for (int q = 0; q < 4; ++q) {
        __syncthreads();                       // buf[q&1] fully staged for all waves
        if (q < 3) STAGE(q + 1, sm + ((q + 1) & 1) * 15840);   // loads in flight during MFMAs
        const unsigned short* sb = sm + (q & 1) * 15840;
#pragma unroll
        for (int tp = 0; tp < 9; ++tp) {
            int dy = tp / 3, dx = tp % 3;
            bf16x8 afr[2];
#pragma unroll
            for (int mq = 0; mq < 2; ++mq) {
                int off = ((py + dy) * 66 + xh + mq * 16 + l15 + dx) * 40 + quad * 8;
                afr[mq] = *(const bf16x8*)(&sb[off]);
            }
            const unsigned short* wb = wf + (size_t)((q * 9 + tp) * 6) * 512 + lane * 8;
#pragma unroll
            for (int nb = 0; nb < 6; ++nb) {
                bf16x8 bfr = *(const bf16x8*)(wb + nb * 512);
                acc[0][nb] = __builtin_amdgcn_mfma_f32_16x16x32_bf16(afr[0], bfr, acc[0][nb], 0, 0, 0);
                acc[1][nb] = __builtin_amdgcn_mfma_f32_16x16x32_bf16(afr[1], bfr, acc[1][nb], 0, 0, 0);
            }
        }
    }
#undef STAGE
    __syncthreads();
    // dump y tile to LDS: pixel p in [0,256), channel in [0,96), stride 98
#pragma unroll
    for (int mq = 0; mq < 2; ++mq) {
#pragma unroll
        for (int nb = 0; nb < 6; ++nb) {
            int ch = nb * 16 + l15;
            int pbase = py * 64 + xh + mq * 16 + quad * 4;
#pragma unroll
            for (int r = 0; r < 4; ++r)
                sm[(pbase + r) * 98 + ch] = f32_to_bf16(acc[mq][nb][r]);
        }
    }
    __syncthreads();
    // unsketch + median-of-3 + write m (coalesced)
    int p = tid & 255;
    int c0 = (tid >> 8) * 64;
    unsigned short* mp = m_out + (size_t)b * Cn * HWn + tile * 256 + p;
#pragma unroll 4
    for (int cc = 0; cc < 64; ++cc) {
        int c = c0 + cc;
        int i0 = idx_sh[c], i1 = idx_sh[128 + c], i2 = idx_sh[256 + c];
        float z0 = ss_sh[c]       * bf16_to_f32(sm[p * 98 + i0]);
        float z1 = ss_sh[128 + c] * bf16_to_f32(sm[p * 98 + 32 + i1]);
        float z2 = ss_sh[256 + c] * bf16_to_f32(sm[p * 98 + 64 + i2]);
        float lo = fminf(z0, z1), hi = fmaxf(z0, z1);
        float med = fmaxf(lo, fminf(hi, z2));
        mp[(size_t)c * HWn] = f32_to_bf16(med);
    }
}

// k_conv needs ss in LDS; small loader kernel argument instead: pass ss and fill
// ss_sh at start. (Implemented via a second pointer arg — see launch.)
__global__ __launch_bounds__(256) void k_stats(const unsigned short* __restrict__ m,
                                               float* __restrict__ stats) {
    int blk = blockIdx.x;            // c*4 + bq
    int c = blk >> 2, bq = blk & 3;
    int tid = threadIdx.x;
    float s = 0.f, s2 = 0.f;
    for (int b = bq * 8; b < bq * 8 + 8; ++b) {
        const ushort4* mp = (const ushort4*)(m + (size_t)(b * Cn + c) * HWn);
#pragma unroll
        for (int i = 0; i < 4; ++i) {
            ushort4 v = mp[i * 256 + tid];
            float a0 = bf16_to_f32(v.x), a1 = bf16_to_f32(v.y);
            float a2 = bf16_to_f32(v.z), a3 = bf16_to_f32(v.w);
            s  += a0 + a1 + a2 + a3;
            s2 += a0 * a0 + a1 * a1 + a2 * a2 + a3 * a3;
        }
    }
    for (int o = 32; o > 0; o >>= 1) { s += __shfl_down(s, o); s2 += __shfl_down(s2, o); }
    __shared__ float rs[8];
    if ((tid & 63) == 0) { rs[tid >> 6] = s; rs[4 + (tid >> 6)] = s2; }
    __syncthreads();
    if (tid == 0) {
        float S = rs[0] + rs[1] + rs[2] + rs[3];
        float S2 = rs[4] + rs[5] + rs[6] + rs[7];
        atomicAdd(&stats[c], S);
        atomicAdd(&stats[128 + c], S2);
    }
}

// ---- K3b: finalize BN coefficients ----
__global__ void k_bn(const float* __restrict__ stats, const float* __restrict__ gamma,
                     const float* __restrict__ beta, float* __restrict__ bn) {
    int c = threadIdx.x;
    if (c < 128) {
        const float N = 131072.f;
        float mean = stats[c] / N;
        float var  = stats[128 + c] / N - mean * mean;
        float sc   = gamma[c] * rsqrtf(var + 1e-5f);
        bn[c] = sc;
        bn[128 + c] = beta[c] - mean * sc;
    }
}

// ---- K4: out = relu(m*sc+sh) + x ----
__global__ __launch_bounds__(256) void k_apply(const unsigned short* __restrict__ m,
                                               const float* __restrict__ x,
                                               const float* __restrict__ bn,
                                               float* __restrict__ out) {
    int i4 = blockIdx.x * 256 + threadIdx.x;      // 4,194,304 groups of 4
    size_t base = (size_t)i4 * 4;
    int c = (int)((base >> 12) & 127);
    float sc = bn[c], sh = bn[128 + c];
    ushort4 mv = ((const ushort4*)m)[i4];
    float4  xv = ((const float4*)x)[i4];
    float4 o;
    o.x = fmaxf(bf16_to_f32(mv.x) * sc + sh, 0.f) + xv.x;
    o.y = fmaxf(bf16_to_f32(mv.y) * sc + sh, 0.f) + xv.y;
    o.z = fmaxf(bf16_to_f32(mv.z) * sc + sh, 0.f) + xv.z;
    o.w = fmaxf(bf16_to_f32(mv.w) * sc + sh, 0.f) + xv.w;
    ((float4*)out)[i4] = o;
}

extern "C" void kernel_launch(void* const* d_in, const int* in_sizes, int n_in,
                              void* d_out, int out_size, void* d_ws, size_t ws_size,
                              hipStream_t stream);

// k_conv needs ss for the epilogue — wrap with a variant taking ss.
__global__ __launch_bounds__(512, 4) void k_conv_full(const float* __restrict__ x,
                                                      const unsigned short* __restrict__ wf,
                                                      const int* __restrict__ idx,
                                                      const float* __restrict__ ss,
                                                      unsigned short* __restrict__ m_out);

// Definition of the full conv kernel (the one actually launched).
__global__ __launch_bounds__(512, 4) void k_conv_full(const float* __restrict__ x,
                                                      const unsigned short* __restrict__ wf,
                                                      const int* __restrict__ idx,
                                                      const float* __restrict__ ss,
                                                      unsigned short* __restrict__ m_out) {
    __shared__ __align__(16) unsigned short sm[31680];
    __shared__ int   idx_sh[384];
    __shared__ float ss_sh[384];
    int tid  = threadIdx.x;
    int blk  = blockIdx.x;
    int tile = blk & 15, b = blk >> 4;
    int ty0  = tile * 4;
    int wv   = tid >> 6, lane = tid & 63;
    int quad = lane >> 4, l15 = lane & 15;
    int py   = wv >> 1, xh = (wv & 1) * 32;

    for (int i = tid; i < 384; i += 512) { idx_sh[i] = idx[i]; ss_sh[i] = ss[i]; }

    f32x4 acc[2][6];
#pragma unroll
    for (int a = 0; a < 2; ++a)
#pragma unroll
        for (int nb = 0; nb < 6; ++nb) acc[a][nb] = (f32x4){0.f, 0.f, 0.f, 0.f};

#define STAGE(Q, BUF)                                                                   \
    {                                                                                   \
        unsigned short* sb_ = (BUF);                                                    \
        _Pragma("unroll")                                                               \
        for (int t0 = 0; t0 < 1584; t0 += 512) {                                        \
            int t = t0 + tid;                                                           \
            if (t < 1584) {                                                             \
                int r = t >> 2, oct = t & 3;                                            \
                int hy = r / 66, hx = r - hy * 66;                                      \
                int gy = ty0 + hy - 1, gx = hx - 1;                                     \
                unsigned short tmp[8];                                                  \
                if ((unsigned)gy < 64u && (unsigned)gx < 64u) {                         \
                    const float* xp = x + ((size_t)((b * 4 + (Q)) * 32 + oct * 8) << 12) \
                                        + gy * 64 + gx;                                 \
                    _Pragma("unroll")                                                   \
                    for (int i = 0; i < 8; ++i) tmp[i] = f32_to_bf16(xp[(size_t)i << 12]); \
                } else {                                                                \
                    _Pragma("unroll")                                                   \
                    for (int i = 0; i < 8; ++i) tmp[i] = 0;                             \
                }                                                                       \
                *(uint4*)(&sb_[r * 40 + oct * 8]) = *(const uint4*)tmp;                 \
            }                                                                           \
        }                                                                               \
    }

    STAGE(0, sm);
#pragma unroll
    for (int q = 0; q < 4; ++q) {
        __syncthreads();
        if (q < 3) STAGE(q + 1, sm + ((q + 1) & 1) * 15840);
        const unsigned short* sb = sm + (q & 1) * 15840;
#pragma unroll
        for (int tp = 0; tp < 9; ++tp) {
            int dy = tp / 3, dx = tp % 3;
            bf16x8 afr[2];
#pragma unroll
            for (int mq = 0; mq < 2; ++mq) {
                int off = ((py + dy) * 66 + xh + mq * 16 + l15 + dx) * 40 + quad * 8;
                afr[mq] = *(const bf16x8*)(&sb[off]);
            }
            const unsigned short* wb = wf + (size_t)((q * 9 + tp) * 6) * 512 + lane * 8;
#pragma unroll
            for (int nb = 0; nb < 6; ++nb) {
                bf16x8 bfr = *(const bf16x8*)(wb + nb * 512);
                acc[0][nb] = __builtin_amdgcn_mfma_f32_16x16x32_bf16(afr[0], bfr, acc[0][nb], 0, 0, 0);
                acc[1][nb] = __builtin_amdgcn_mfma_f32_16x16x32_bf16(afr[1], bfr, acc[1][nb], 0, 0, 0);
            }
        }
    }
#undef STAGE
    __syncthreads();
#pragma unroll
    for (int mq = 0; mq < 2; ++mq) {
#pragma unroll
        for (int nb = 0; nb < 6; ++nb) {
            int ch = nb * 16 + l15;
            int pbase = py * 64 + xh + mq * 16 + quad * 4;
#pragma unroll
            for (int r = 0; r < 4; ++r)
                sm[(pbase + r) * 98 + ch] = f32_to_bf16(acc[mq][nb][r]);
        }
    }
    __syncthreads();
    int p = tid & 255;
    int c0 = (tid >> 8) * 64;
    unsigned short* mp = m_out + (size_t)b * Cn * HWn + tile * 256 + p;
#pragma unroll 4
    for (int cc = 0; cc < 64; ++cc) {
        int c = c0 + cc;
        int i0 = idx_sh[c], i1 = idx_sh[128 + c], i2 = idx_sh[256 + c];
        float z0 = ss_sh[c]       * bf16_to_f32(sm[p * 98 + i0]);
        float z1 = ss_sh[128 + c] * bf16_to_f32(sm[p * 98 + 32 + i1]);
        float z2 = ss_sh[256 + c] * bf16_to_f32(sm[p * 98 + 64 + i2]);
        float lo = fminf(z0, z1), hi = fmaxf(z0, z1);
        float med = fmaxf(lo, fminf(hi, z2));
        mp[(size_t)c * HWn] = f32_to_bf16(med);
    }
}

extern "C" void kernel_launch(void* const* d_in, const int* in_sizes, int n_in,
                              void* d_out, int out_size, void* d_ws, size_t ws_size,
                              hipStream_t stream) {
    const float* x      = (const float*)d_in[0];
    // d_in[1] = w1, d_in[3] = gamma1, d_in[4] = beta1 : dead code in the reference
    const float* w2     = (const float*)d_in[2];
    const float* gamma2 = (const float*)d_in[5];
    const float* beta2  = (const float*)d_in[6];
    const float* hs     = (const float*)d_in[7];
    const float* ss     = (const float*)d_in[8];
    float* out = (float*)d_out;

    char* ws = (char*)d_ws;
    unsigned short* wfp = (unsigned short*)(ws + OFF_WF);
    int*            idp = (int*)(ws + OFF_IDX);
    unsigned short* mp  = (unsigned short*)(ws + OFF_M);
    float*          st  = (float*)(ws + OFF_STATS);
    float*          bnp = (float*)(ws + OFF_BN);

    hipMemsetAsync(st, 0, 1024, stream);
    k_idx<<<2, 256, 0, stream>>>(hs, idp);
    k_wsk<<<432, 256, 0, stream>>>(w2, hs, ss, wfp);
    k_conv_full<<<512, 512, 0, stream>>>(x, wfp, idp, ss, mp);
    k_stats<<<512, 256, 0, stream>>>(mp, st);
    k_bn<<<1, 128, 0, stream>>>(st, gamma2, beta2, bnp);
    k_apply<<<16384, 256, 0, stream>>>(mp, x, bnp, out);
}

// Round 4
// 231.661 us; speedup vs baseline: 1.0066x; 1.0066x over previous
//
#include <hip/hip_runtime.h>
#include <stdint.h>

typedef __bf16 bf16x8 __attribute__((ext_vector_type(8)));
typedef float  f32x4  __attribute__((ext_vector_type(4)));

static constexpr int Bn = 32, Cn = 128, Hn = 64, Wn = 64, HWn = 4096;
static constexpr size_t OFF_XT    = 0;                        // 33,554,432 B (bf16 x, chunk-major NHWC)
static constexpr size_t OFF_WF    = 33554432;                 // 221,184 B (B-fragment-ordered weights)
static constexpr size_t OFF_IDX   = 33775616;                 // 1,536 B
static constexpr size_t OFF_M     = 33777152;                 // 33,554,432 B (median result, bf16, NCHW)
static constexpr size_t OFF_STATS = 67331584;                 // 1,024 B
static constexpr size_t OFF_BN    = 67332608;                 // 1,024 B

__device__ __forceinline__ unsigned short f32_to_bf16(float f) {
    union { float f; unsigned u; } v; v.f = f;
    unsigned u = v.u;
    return (unsigned short)((u + 0x7FFFu + ((u >> 16) & 1u)) >> 16);
}
__device__ __forceinline__ float bf16_to_f32(unsigned short h) {
    union { unsigned u; float f; } v; v.u = ((unsigned)h) << 16;
    return v.f;
}

// async global->LDS DMA, 16B per lane; lds dest = wave-uniform base + lane*16
__device__ __forceinline__ void load_lds16(const unsigned short* g, unsigned short* l) {
    __builtin_amdgcn_global_load_lds((const __attribute__((address_space(1))) unsigned int*)g,
                                     (__attribute__((address_space(3))) unsigned int*)l,
                                     16, 0, 0);
}

// ---- K0: x NCHW fp32 -> xT[b][q][y][x][32ci] bf16 (chunk-major NHWC) ----
__global__ __launch_bounds__(256) void k_transpose(const float* __restrict__ x,
                                                   unsigned short* __restrict__ xT) {
    __shared__ __align__(16) unsigned short sm[256 * 40];
    int blk = blockIdx.x;                 // b*64 + q*16 + pt
    int pt = blk & 15, q = (blk >> 4) & 3, b = blk >> 6;
    int p0 = pt * 256;
    int t = threadIdx.x;
    const float* xp = x + ((size_t)(b * Cn + q * 32) * HWn) + p0 + t;
#pragma unroll
    for (int cil = 0; cil < 32; ++cil)
        sm[t * 40 + cil] = f32_to_bf16(xp[(size_t)cil * HWn]);
    __syncthreads();
    uint4* dst = (uint4*)(xT + ((size_t)(b * 4 + q) * HWn + p0) * 32);
#pragma unroll
    for (int pass = 0; pass < 4; ++pass) {
        int pix = pass * 64 + (t >> 2);
        int ch  = t & 3;
        dst[pix * 4 + ch] = *(const uint4*)(&sm[pix * 40 + ch * 8]);
    }
}

// ---- K1a: recover idx[j][c] from one-hot hs (3,32,128) ----
__global__ void k_idx(const float* __restrict__ hs, int* __restrict__ idx) {
    int t = blockIdx.x * 256 + threadIdx.x;
    if (t >= 384) return;
    int j = t >> 7, c = t & 127;
    int found = 0;
    for (int d = 0; d < 32; ++d)
        if (hs[(j * 32 + d) * 128 + c] > 0.5f) found = d;
    idx[t] = found;
}

// ---- K1b: sketched weights in MFMA B-fragment order ----
// One block per output channel n = j*32+d. Block-uniform branch on idx match;
// w2 row reads fully coalesced (1152 consecutive floats).
// frag layout: f = ((q*9+t)*6+nt)*512 + lane*8 + jj holds B[k=(lane>>4)*8+jj][n=nt*16+(lane&15)]
__global__ __launch_bounds__(256) void k_wsk(const float* __restrict__ w2,
                                             const int* __restrict__ idx,
                                             const float* __restrict__ ss,
                                             unsigned short* __restrict__ wf) {
    int n = blockIdx.x;                   // 0..95
    int j = n >> 5, d = n & 31;
    __shared__ int   idb[128];
    __shared__ float ssb[128];
    int tid = threadIdx.x;
    if (tid < 128) { idb[tid] = idx[j * 128 + tid]; ssb[tid] = ss[j * 128 + tid]; }
    __syncthreads();
    float acc[5] = {0.f, 0.f, 0.f, 0.f, 0.f};
    for (int c = 0; c < 128; ++c) {
        if (idb[c] == d) {                // block-uniform branch (~4 taken of 128)
            float s = ssb[c];
            const float* wr = w2 + (size_t)c * 1152;
#pragma unroll
            for (int e = 0; e < 5; ++e) {
                int i = e * 256 + tid;
                if (i < 1152) acc[e] += s * wr[i];
            }
        }
    }
    int nt = n >> 4, l15 = n & 15;
#pragma unroll
    for (int e = 0; e < 5; ++e) {
        int i = e * 256 + tid;
        if (i < 1152) {
            int ci = i / 9, t = i - ci * 9;
            int q = ci >> 5, k = ci & 31;
            int lane = ((k >> 3) << 4) | l15, jj = k & 7;
            wf[((size_t)((q * 9 + t) * 6 + nt)) * 512 + lane * 8 + jj] = f32_to_bf16(acc[e]);
        }
    }
}

// ---- K2: conv(96ch) + unsketch + median3 -> m (bf16, NCHW) ----
// grid 512 = b*16 + tile; tile = 4 rows x 64 cols; 4 waves, wave wv owns row wv.
// K-chunks q=0..3 (32 ci each): double-buffered LDS staging via async
// global_load_lds (no VGPR round-trip), ONE barrier per chunk.
// LDS buf: 396 records (6 rows x 66 cols) x 32 ci x bf16 = 12672 elems, unpadded
// (A-frag ds_read_b128 with lanes on consecutive 64B records is conflict-free).
__global__ __launch_bounds__(256) void k_conv(const unsigned short* __restrict__ xT,
                                              const unsigned short* __restrict__ wf,
                                              const int* __restrict__ idx,
                                              const float* __restrict__ ss,
                                              unsigned short* __restrict__ m_out) {
    __shared__ __align__(16) unsigned short sm[25344];   // 2 x 12672; y-tile (25088) aliases
    __shared__ int   idx_sh[384];
    __shared__ float ss_sh[384];
    int tid  = threadIdx.x;
    int blk  = blockIdx.x;
    int tile = blk & 15, b = blk >> 4;
    int ty0  = tile * 4;
    int wv   = tid >> 6, lane = tid & 63;
    int quad = lane >> 4, l15 = lane & 15;

    for (int i = tid; i < 384; i += 256) { idx_sh[i] = idx[i]; ss_sh[i] = ss[i]; }
    // zero both staging buffers once: halo OOB cells are at fixed, q-independent
    // positions and are never touched by the exec-masked DMA below.
    {
        uint4 z = {0u, 0u, 0u, 0u};
        uint4* smv = (uint4*)sm;
#pragma unroll
        for (int u = tid; u < 3168; u += 256) smv[u] = z;
    }
    __syncthreads();

    f32x4 acc[4][6];
#pragma unroll
    for (int a = 0; a < 4; ++a)
#pragma unroll
        for (int nb = 0; nb < 6; ++nb) acc[a][nb] = (f32x4){0.f, 0.f, 0.f, 0.f};

    // stage chunk Q into buffer at elem-offset SBOFF: 1584 lane-units of 16B
#define STAGE_ASYNC(Q, SBOFF)                                                           \
    {                                                                                   \
        const unsigned short* gch = xT + (((size_t)(b * 4 + (Q))) << 12) * 32;          \
        _Pragma("unroll")                                                               \
        for (int t0 = 0; t0 < 1584; t0 += 256) {                                        \
            int u = t0 + tid;                                                           \
            unsigned short* lb = sm + (SBOFF) + (size_t)(t0 + (tid & ~63)) * 8;         \
            if (u < 1584) {                                                             \
                int r = u >> 2, c16 = u & 3;                                            \
                int hy = r / 66, hx = r - hy * 66;                                      \
                int gy = ty0 + hy - 1, gx = hx - 1;                                     \
                if ((unsigned)gy < 64u && (unsigned)gx < 64u) {                         \
                    const unsigned short* gp = gch + ((size_t)(gy * 64 + gx)) * 32 + c16 * 8; \
                    load_lds16(gp, lb);                                                 \
                }                                                                       \
            }                                                                           \
        }                                                                               \
    }

    STAGE_ASYNC(0, 0);
    for (int q = 0; q < 4; ++q) {
        __syncthreads();     // staged chunk q landed (compiler drains vmcnt here)
        if (q < 3) STAGE_ASYNC(q + 1, ((q + 1) & 1) * 12672);   // async into other buf
        const unsigned short* sb = sm + (q & 1) * 12672;
#pragma unroll
        for (int tp = 0; tp < 9; ++tp) {
            int dy = tp / 3, dx = tp % 3;
            bf16x8 afr[4];
#pragma unroll
            for (int mq = 0; mq < 4; ++mq) {
                int off = ((wv + dy) * 66 + mq * 16 + l15 + dx) * 32 + quad * 8;
                afr[mq] = *(const bf16x8*)(&sb[off]);
            }
            const unsigned short* wb = wf + (size_t)((q * 9 + tp) * 6) * 512 + lane * 8;
#pragma unroll
            for (int nb = 0; nb < 6; ++nb) {
                bf16x8 bfr = *(const bf16x8*)(wb + nb * 512);
#pragma unroll
                for (int mq = 0; mq < 4; ++mq)
                    acc[mq][nb] = __builtin_amdgcn_mfma_f32_16x16x32_bf16(afr[mq], bfr, acc[mq][nb], 0, 0, 0);
            }
        }
    }
#undef STAGE_ASYNC
    __syncthreads();
    // dump y tile to LDS: pixel p in [0,256), channel in [0,96), stride 98
#pragma unroll
    for (int mq = 0; mq < 4; ++mq) {
#pragma unroll
        for (int nb = 0; nb < 6; ++nb) {
            int ch = nb * 16 + l15;
            int pbase = wv * 64 + mq * 16 + quad * 4;
#pragma unroll
            for (int r = 0; r < 4; ++r)
                sm[(pbase + r) * 98 + ch] = f32_to_bf16(acc[mq][nb][r]);
        }
    }
    __syncthreads();
    // unsketch + median-of-3 + write m (coalesced)
    int p = tid;
    unsigned short* mp = m_out + (size_t)b * Cn * HWn + tile * 256 + p;
#pragma unroll 4
    for (int c = 0; c < 128; ++c) {
        int i0 = idx_sh[c], i1 = idx_sh[128 + c], i2 = idx_sh[256 + c];
        float z0 = ss_sh[c]       * bf16_to_f32(sm[p * 98 + i0]);
        float z1 = ss_sh[128 + c] * bf16_to_f32(sm[p * 98 + 32 + i1]);
        float z2 = ss_sh[256 + c] * bf16_to_f32(sm[p * 98 + 64 + i2]);
        float lo = fminf(z0, z1), hi = fmaxf(z0, z1);
        float med = fmaxf(lo, fminf(hi, z2));
        mp[(size_t)c * HWn] = f32_to_bf16(med);
    }
}

// ---- K3a: per-channel sum / sumsq of m ----
__global__ __launch_bounds__(256) void k_stats(const unsigned short* __restrict__ m,
                                               float* __restrict__ stats) {
    int blk = blockIdx.x;            // c*4 + bq
    int c = blk >> 2, bq = blk & 3;
    int tid = threadIdx.x;
    float s = 0.f, s2 = 0.f;
    for (int b = bq * 8; b < bq * 8 + 8; ++b) {
        const ushort4* mp = (const ushort4*)(m + (size_t)(b * Cn + c) * HWn);
#pragma unroll
        for (int i = 0; i < 4; ++i) {
            ushort4 v = mp[i * 256 + tid];
            float a0 = bf16_to_f32(v.x), a1 = bf16_to_f32(v.y);
            float a2 = bf16_to_f32(v.z), a3 = bf16_to_f32(v.w);
            s  += a0 + a1 + a2 + a3;
            s2 += a0 * a0 + a1 * a1 + a2 * a2 + a3 * a3;
        }
    }
    for (int o = 32; o > 0; o >>= 1) { s += __shfl_down(s, o); s2 += __shfl_down(s2, o); }
    __shared__ float rs[8];
    if ((tid & 63) == 0) { rs[tid >> 6] = s; rs[4 + (tid >> 6)] = s2; }
    __syncthreads();
    if (tid == 0) {
        float S = rs[0] + rs[1] + rs[2] + rs[3];
        float S2 = rs[4] + rs[5] + rs[6] + rs[7];
        atomicAdd(&stats[c], S);
        atomicAdd(&stats[128 + c], S2);
    }
}

// ---- K3b: finalize BN coefficients ----
__global__ void k_bn(const float* __restrict__ stats, const float* __restrict__ gamma,
                     const float* __restrict__ beta, float* __restrict__ bn) {
    int c = threadIdx.x;
    if (c < 128) {
        const float N = 131072.f;
        float mean = stats[c] / N;
        float var  = stats[128 + c] / N - mean * mean;
        float sc   = gamma[c] * rsqrtf(var + 1e-5f);
        bn[c] = sc;
        bn[128 + c] = beta[c] - mean * sc;
    }
}

// ---- K4: out = relu(m*sc+sh) + x ----
__global__ __launch_bounds__(256) void k_apply(const unsigned short* __restrict__ m,
                                               const float* __restrict__ x,
                                               const float* __restrict__ bn,
                                               float* __restrict__ out) {
    int i4 = blockIdx.x * 256 + threadIdx.x;      // 4,194,304 groups of 4
    size_t base = (size_t)i4 * 4;
    int c = (int)((base >> 12) & 127);
    float sc = bn[c], sh = bn[128 + c];
    ushort4 mv = ((const ushort4*)m)[i4];
    float4  xv = ((const float4*)x)[i4];
    float4 o;
    o.x = fmaxf(bf16_to_f32(mv.x) * sc + sh, 0.f) + xv.x;
    o.y = fmaxf(bf16_to_f32(mv.y) * sc + sh, 0.f) + xv.y;
    o.z = fmaxf(bf16_to_f32(mv.z) * sc + sh, 0.f) + xv.z;
    o.w = fmaxf(bf16_to_f32(mv.w) * sc + sh, 0.f) + xv.w;
    ((float4*)out)[i4] = o;
}

extern "C" void kernel_launch(void* const* d_in, const int* in_sizes, int n_in,
                              void* d_out, int out_size, void* d_ws, size_t ws_size,
                              hipStream_t stream) {
    const float* x      = (const float*)d_in[0];
    // d_in[1] = w1, d_in[3] = gamma1, d_in[4] = beta1 : dead code in the reference
    const float* w2     = (const float*)d_in[2];
    const float* gamma2 = (const float*)d_in[5];
    const float* beta2  = (const float*)d_in[6];
    const float* hs     = (const float*)d_in[7];
    const float* ss     = (const float*)d_in[8];
    float* out = (float*)d_out;

    char* ws = (char*)d_ws;
    unsigned short* xT  = (unsigned short*)(ws + OFF_XT);
    unsigned short* wfp = (unsigned short*)(ws + OFF_WF);
    int*            idp = (int*)(ws + OFF_IDX);
    unsigned short* mp  = (unsigned short*)(ws + OFF_M);
    float*          st  = (float*)(ws + OFF_STATS);
    float*          bnp = (float*)(ws + OFF_BN);

    hipMemsetAsync(st, 0, 1024, stream);
    k_transpose<<<2048, 256, 0, stream>>>(x, xT);
    k_idx<<<2, 256, 0, stream>>>(hs, idp);
    k_wsk<<<96, 256, 0, stream>>>(w2, idp, ss, wfp);
    k_conv<<<512, 256, 0, stream>>>(xT, wfp, idp, ss, mp);
    k_stats<<<512, 256, 0, stream>>>(mp, st);
    k_bn<<<1, 128, 0, stream>>>(st, gamma2, beta2, bnp);
    k_apply<<<16384, 256, 0, stream>>>(mp, x, bnp, out);
}